// Round 6
// baseline (538.384 us; speedup 1.0000x reference)
//
#include <hip/hip_runtime.h>
#include <math.h>

typedef __attribute__((ext_vector_type(4)))  int   i32x4;
typedef __attribute__((ext_vector_type(16))) int   i32x16;
typedef __attribute__((ext_vector_type(4)))  float f32x4;

namespace {
constexpr int IN_F   = 4096;
constexpr int OUT_F  = 4096;
constexpr int TOKENS = 8192;
constexpr int PACKED = IN_F / 16;      // 256 words per weight row

// fast-path gemm geometry: small wave tile -> 64 AGPR acc -> 3 blocks/CU
constexpr int BM   = 256;
constexpr int BN   = 64;
constexpr int BK   = 64;               // 4 chunks of 16 k
constexpr int NTHR = 256;              // 4 waves; wave w owns rows [w*64, w*64+64)
constexpr int NT   = IN_F / BK;        // 64 K-tiles

constexpr size_t XQ_BYTES = (size_t)TOKENS * IN_F;        // 33.55 MB
constexpr size_t XS_BYTES = (size_t)TOKENS * 4;           // 32 KB
constexpr size_t BQ_OFF   = XQ_BYTES + XS_BYTES;
constexpr size_t BQ_BYTES = (size_t)PACKED * OUT_F * 16;  // 16.78 MB
constexpr size_t WS_NEED  = BQ_OFF + BQ_BYTES;            // ~50.4 MB
}

// 16x 2-bit {0,1,2}  ->  16x i8 {-1,0,1}  (4 dwords)
__device__ __forceinline__ i32x4 unpack16(unsigned w) {
  i32x4 r;
#pragma unroll
  for (int g = 0; g < 4; ++g) {
    unsigned t = (w >> (8 * g)) & 0xFFu;
    unsigned s = (t | (t << 6) | (t << 12) | (t << 18)) & 0x03030303u;
    r[g] = (int)((((s | 0x80808080u) - 0x01010101u) ^ 0x80808080u));
  }
  return r;
}

// ---------------- pass 1a: per-row absmax + i8 quantize ----------------
// One wave per row (4 rows/block). Lane i: 16B at c*1024 + i*16 — fully
// coalesced loads AND stores (1 KB/wave-instr).
__global__ __launch_bounds__(256)
void rowquant(const float* __restrict__ X, signed char* __restrict__ XQ,
              float* __restrict__ XS) {
  const int row  = blockIdx.x * 4 + (threadIdx.x >> 6);
  const int lane = threadIdx.x & 63;
  const float* xr = X + (size_t)row * IN_F;

  f32x4 v[16];
  float m = 0.f;
#pragma unroll
  for (int c = 0; c < 16; ++c) {
    v[c] = *(const f32x4*)(xr + c * 256 + lane * 4);
    m = fmaxf(m, fmaxf(fmaxf(fabsf(v[c].x), fabsf(v[c].y)),
                       fmaxf(fabsf(v[c].z), fabsf(v[c].w))));
  }
#pragma unroll
  for (int off = 32; off; off >>= 1) m = fmaxf(m, __shfl_xor(m, off, 64));
  m = fmaxf(m, 1e-5f);
  const float r = 127.f / m;

#pragma unroll
  for (int c = 0; c < 16; ++c) {
    int q0 = (int)rintf(v[c].x * r);
    int q1 = (int)rintf(v[c].y * r);
    int q2 = (int)rintf(v[c].z * r);
    int q3 = (int)rintf(v[c].w * r);
    unsigned d = (q0 & 255) | ((q1 & 255) << 8) | ((q2 & 255) << 16) | ((q3 & 255) << 24);
    *(unsigned*)(XQ + (size_t)row * IN_F + c * 256 + lane * 4) = d;
  }
  if (lane == 0) XS[row] = m;
}

// ---------------- pass 1b: unpack ternary B once -> i8, chunk-major ----
// BQ layout: [c (k/16)][n][16 bytes]
__global__ __launch_bounds__(256)
void unpackB(const unsigned* __restrict__ PW, signed char* __restrict__ BQ) {
  const int g = blockIdx.x * 256 + threadIdx.x;   // 1M words
  const int c = g >> 12;                           // 0..255
  const int n = g & 4095;
  i32x4 u = unpack16(PW[(size_t)n * PACKED + c]);
  *(i32x4*)(BQ + ((size_t)c * OUT_F + n) * 16) = u;
}

// ---------------- pass 2 (fast): i8 GEMM, occupancy-tuned pipeline -----
// Per wave per K-tile: 4 global_load_lds (stage chunk w of next tile) +
// 4 B reg loads -> exactly 8 vmem ops -> counted vmcnt(8) waits ONLY on
// the previous tile (never on just-issued HBM loads).

#define STAGE_A(BUF, KT)                                                        \
  {                                                                             \
    _Pragma("unroll")                                                           \
    for (int rb = 0; rb < 4; ++rb) {                                            \
      const signed char* src =                                                  \
          XQ + (size_t)(m0 + rb * 64 + lane) * IN_F + (KT) * BK + w * 16;       \
      signed char* dst = lA + (BUF) * 16384 + w * 4096 + rb * 1024;             \
      __builtin_amdgcn_global_load_lds(                                         \
          (const __attribute__((address_space(1))) void*)src,                   \
          (__attribute__((address_space(3))) void*)dst, 16, 0, 0);              \
    }                                                                           \
  }

#define LOAD_B(B, KT)                                                           \
  {                                                                             \
    _Pragma("unroll")                                                           \
    for (int nf = 0; nf < 2; ++nf) {                                            \
      _Pragma("unroll")                                                         \
      for (int ks = 0; ks < 2; ++ks)                                            \
        B[nf][ks] = *(const i32x4*)(BQ +                                        \
            ((size_t)((KT) * 4 + ks * 2 + h) * OUT_F + nrow[nf]) * 16);         \
      }                                                                         \
  }

#define COMPUTE_TILE(BUFOFF, B)                                                 \
  {                                                                             \
    _Pragma("unroll")                                                           \
    for (int ks = 0; ks < 2; ++ks) {                                            \
      i32x4 afr[2];                                                             \
      _Pragma("unroll")                                                         \
      for (int mf = 0; mf < 2; ++mf)                                            \
        afr[mf] = *(const i32x4*)(lA + (BUFOFF) + (ks * 2 + h) * 4096 +         \
                                  (w * 64 + mf * 32 + l31) * 16);               \
      __builtin_amdgcn_s_setprio(1);                                            \
      _Pragma("unroll")                                                         \
      for (int mf = 0; mf < 2; ++mf) {                                          \
        acc[mf][0] = __builtin_amdgcn_mfma_i32_32x32x32_i8(afr[mf], B[0][ks],   \
                                                           acc[mf][0], 0, 0, 0);\
        acc[mf][1] = __builtin_amdgcn_mfma_i32_32x32x32_i8(afr[mf], B[1][ks],   \
                                                           acc[mf][1], 0, 0, 0);\
      }                                                                         \
      __builtin_amdgcn_s_setprio(0);                                            \
    }                                                                           \
  }

__global__ __launch_bounds__(NTHR, 3)
void gemm_i8(const signed char* __restrict__ XQ, const signed char* __restrict__ BQ,
             const float* __restrict__ XS, const float* __restrict__ SC,
             float* __restrict__ OUT) {
  __shared__ signed char lA[2 * 16384];

  const int tid  = threadIdx.x;
  const int lane = tid & 63;
  const int w    = tid >> 6;     // 0..3: wave owns rows [w*64, w*64+64)
  const int l31  = lane & 31;
  const int h    = lane >> 5;    // half-wave -> k-chunk parity

  // bijective XCD swizzle: 2048 blocks, 256/XCD; each XCD owns 8 n-tiles
  // (BQ stripe = 256 chunks x 512 n x 16B = 2 MB < 4 MB L2)
  const int orig = blockIdx.y * gridDim.x + blockIdx.x;
  const int xcd  = orig & 7;
  const int idx  = orig >> 3;                  // 0..255
  const int m0   = (idx >> 3) * BM;            // 32 m-tiles
  const int n0   = (xcd * 8 + (idx & 7)) * BN; // 64 n-tiles

  const int nrow[2] = { n0 + 0 * 32 + l31, n0 + 1 * 32 + l31 };

  i32x16 acc[2][2];
#pragma unroll
  for (int mf = 0; mf < 2; ++mf)
#pragma unroll
    for (int nf = 0; nf < 2; ++nf)
      acc[mf][nf] = (i32x16)(0);

  i32x4 Ba[2][2], Bb[2][2];

  // prologue: tile 0 in flight (8 vmem ops this wave)
  STAGE_A(0, 0);
  LOAD_B(Ba, 0);

  for (int kt = 0; kt < NT; kt += 2) {
    // ---- even tile: prefetch kt+1, compute buf0/Ba ----
    STAGE_A(1, kt + 1);
    LOAD_B(Bb, kt + 1);
    asm volatile("s_waitcnt vmcnt(8)" ::: "memory");   // tile kt resident
    __builtin_amdgcn_s_barrier();
    COMPUTE_TILE(0, Ba);
    asm volatile("" ::: "memory");
    __builtin_amdgcn_s_barrier();                      // buf0 free

    // ---- odd tile: prefetch kt+2, compute buf1/Bb ----
    if (kt + 2 < NT) {
      STAGE_A(0, kt + 2);
      LOAD_B(Ba, kt + 2);
      asm volatile("s_waitcnt vmcnt(8)" ::: "memory"); // tile kt+1 resident
    } else {
      asm volatile("s_waitcnt vmcnt(0)" ::: "memory"); // final drain
    }
    __builtin_amdgcn_s_barrier();
    COMPUTE_TILE(16384, Bb);
    asm volatile("" ::: "memory");
    __builtin_amdgcn_s_barrier();
  }

  // ---- epilogue: C/D (32x32): col=lane&31, row=(reg&3)+8*(reg>>2)+4*h ----
  const float sc = SC[0] / 127.f;
#pragma unroll
  for (int mf = 0; mf < 2; ++mf) {
    float fs[16];
#pragma unroll
    for (int r = 0; r < 16; ++r) {
      const int mm = m0 + w * 64 + mf * 32 + 4 * h + (r & 3) + 8 * (r >> 2);
      fs[r] = sc * XS[mm];
    }
#pragma unroll
    for (int nf = 0; nf < 2; ++nf) {
      const int ncol = n0 + nf * 32 + l31;
#pragma unroll
      for (int r = 0; r < 16; ++r) {
        const int mm = m0 + w * 64 + mf * 32 + 4 * h + (r & 3) + 8 * (r >> 2);
        OUT[(size_t)mm * OUT_F + ncol] = (float)acc[mf][nf][r] * fs[r];
      }
    }
  }
}

// ------- pass 2 (fallback, ws-small): verified baseline gemm, inline B -------
// Own geometry: 256x128 tile, BK=128, 4 waves (2M x 2N).
__global__ __launch_bounds__(256, 2)
void gemm_i8_pw(const signed char* __restrict__ XQ, const unsigned* __restrict__ PW,
                const float* __restrict__ XS, const float* __restrict__ SC,
                float* __restrict__ OUT) {
  __shared__ signed char lA[256 * 128];

  const int tid  = threadIdx.x;
  const int lane = tid & 63;
  const int w    = tid >> 6;
  const int wm   = w >> 1;
  const int wn   = w & 1;
  const int l31  = lane & 31;
  const int h    = lane >> 5;

  const int m0 = blockIdx.y * 256;
  const int n0 = blockIdx.x * 128;

  i32x16 acc[4][2];
#pragma unroll
  for (int mf = 0; mf < 4; ++mf)
#pragma unroll
    for (int nf = 0; nf < 2; ++nf)
      acc[mf][nf] = (i32x16)(0);

  const unsigned* pb0 = PW + (size_t)(n0 + wn * 64 + 0 * 32 + l31) * PACKED;
  const unsigned* pb1 = PW + (size_t)(n0 + wn * 64 + 1 * 32 + l31) * PACKED;

  for (int kt = 0; kt < IN_F / 128; ++kt) {
#pragma unroll
    for (int cc = 0; cc < 2; ++cc) {
      const int c = w * 2 + cc;
#pragma unroll
      for (int rb = 0; rb < 4; ++rb) {
        const signed char* src =
            XQ + (size_t)(m0 + rb * 64 + lane) * IN_F + kt * 128 + c * 16;
        signed char* dst = lA + c * 4096 + rb * 1024;
        __builtin_amdgcn_global_load_lds(
            (const __attribute__((address_space(1))) void*)src,
            (__attribute__((address_space(3))) void*)dst, 16, 0, 0);
      }
    }

    unsigned bw0[4], bw1[4];
#pragma unroll
    for (int ks = 0; ks < 4; ++ks) {
      bw0[ks] = pb0[kt * 8 + ks * 2 + h];
      bw1[ks] = pb1[kt * 8 + ks * 2 + h];
    }

    __syncthreads();

#pragma unroll
    for (int ks = 0; ks < 4; ++ks) {
      i32x4 bfr0 = unpack16(bw0[ks]);
      i32x4 bfr1 = unpack16(bw1[ks]);
      i32x4 afr[4];
#pragma unroll
      for (int mf = 0; mf < 4; ++mf)
        afr[mf] = *(const i32x4*)(lA + (ks * 2 + h) * 4096 +
                                  (wm * 128 + mf * 32 + l31) * 16);
#pragma unroll
      for (int mf = 0; mf < 4; ++mf) {
        acc[mf][0] = __builtin_amdgcn_mfma_i32_32x32x32_i8(afr[mf], bfr0, acc[mf][0], 0, 0, 0);
        acc[mf][1] = __builtin_amdgcn_mfma_i32_32x32x32_i8(afr[mf], bfr1, acc[mf][1], 0, 0, 0);
      }
    }
    __syncthreads();
  }

  const float sc = SC[0] / 127.f;
#pragma unroll
  for (int mf = 0; mf < 4; ++mf) {
    float fs[16];
#pragma unroll
    for (int r = 0; r < 16; ++r) {
      const int mm = m0 + wm * 128 + mf * 32 + 4 * h + (r & 3) + 8 * (r >> 2);
      fs[r] = sc * XS[mm];
    }
#pragma unroll
    for (int nf = 0; nf < 2; ++nf) {
      const int ncol = n0 + wn * 64 + nf * 32 + l31;
#pragma unroll
      for (int r = 0; r < 16; ++r) {
        const int mm = m0 + wm * 128 + mf * 32 + 4 * h + (r & 3) + 8 * (r >> 2);
        OUT[(size_t)mm * OUT_F + ncol] = (float)acc[mf][nf][r] * fs[r];
      }
    }
  }
}

extern "C" void kernel_launch(void* const* d_in, const int* in_sizes, int n_in,
                              void* d_out, int out_size, void* d_ws, size_t ws_size,
                              hipStream_t stream) {
  const float*    x  = (const float*)d_in[0];
  const unsigned* pw = (const unsigned*)d_in[1];
  const float*    sc = (const float*)d_in[2];
  float*          out = (float*)d_out;

  signed char* xq = (signed char*)d_ws;
  float*       xs = (float*)((char*)d_ws + XQ_BYTES);

  rowquant<<<dim3(TOKENS / 4), dim3(256), 0, stream>>>(x, xq, xs);

  if (ws_size >= WS_NEED) {
    // fast path: pre-unpacked B + occupancy-tuned pipelined gemm
    signed char* bq = (signed char*)d_ws + BQ_OFF;
    unpackB<<<dim3(OUT_F * PACKED / 256), dim3(256), 0, stream>>>(pw, bq);
    dim3 grid(OUT_F / BN, TOKENS / BM);  // (64, 32)
    gemm_i8<<<grid, dim3(NTHR), 0, stream>>>(xq, bq, xs, sc, out);
  } else {
    // fallback: verified baseline gemm, inline ternary unpack (fits 33.6 MB ws)
    dim3 grid(OUT_F / 128, TOKENS / 256);  // (32, 32)
    gemm_i8_pw<<<grid, dim3(256), 0, stream>>>(xq, pw, xs, sc, out);
  }
}

// Round 8
// 426.781 us; speedup vs baseline: 1.2615x; 1.2615x over previous
//
#include <hip/hip_runtime.h>
#include <math.h>

typedef __attribute__((ext_vector_type(4)))  int   i32x4;
typedef __attribute__((ext_vector_type(16))) int   i32x16;
typedef __attribute__((ext_vector_type(4)))  float f32x4;

namespace {
constexpr int IN_F   = 4096;
constexpr int OUT_F  = 4096;
constexpr int TOKENS = 8192;
constexpr int PACKED = IN_F / 16;      // 256 words per weight row

// fast-path gemm: 256x128 block, wave tile 128x64 (acc 128 AGPR), BK=64,
// quad-buffered LDS, prefetch depth 2, one barrier per K-tile.
constexpr int BM   = 256;
constexpr int BN   = 128;
constexpr int BK   = 64;               // 4 chunks of 16 k
constexpr int NTHR = 256;              // 4 waves: 2(M) x 2(N)
constexpr int NT   = IN_F / BK;        // 64 K-tiles

constexpr size_t XQ_BYTES = (size_t)TOKENS * IN_F;        // 33.55 MB
constexpr size_t XS_BYTES = (size_t)TOKENS * 4;           // 32 KB
constexpr size_t BQ_OFF   = XQ_BYTES + XS_BYTES;
constexpr size_t BQ_BYTES = (size_t)PACKED * OUT_F * 16;  // 16.78 MB
constexpr size_t WS_NEED  = BQ_OFF + BQ_BYTES;            // ~50.4 MB
}

// 16x 2-bit {0,1,2}  ->  16x i8 {-1,0,1}  (4 dwords)
__device__ __forceinline__ i32x4 unpack16(unsigned w) {
  i32x4 r;
#pragma unroll
  for (int g = 0; g < 4; ++g) {
    unsigned t = (w >> (8 * g)) & 0xFFu;
    unsigned s = (t | (t << 6) | (t << 12) | (t << 18)) & 0x03030303u;
    r[g] = (int)((((s | 0x80808080u) - 0x01010101u) ^ 0x80808080u));
  }
  return r;
}

// ---------------- pass 1a: per-row absmax + i8 quantize ----------------
__global__ __launch_bounds__(256)
void rowquant(const float* __restrict__ X, signed char* __restrict__ XQ,
              float* __restrict__ XS) {
  const int row  = blockIdx.x * 4 + (threadIdx.x >> 6);
  const int lane = threadIdx.x & 63;
  const float* xr = X + (size_t)row * IN_F;

  f32x4 v[16];
  float m = 0.f;
#pragma unroll
  for (int c = 0; c < 16; ++c) {
    v[c] = *(const f32x4*)(xr + c * 256 + lane * 4);
    m = fmaxf(m, fmaxf(fmaxf(fabsf(v[c].x), fabsf(v[c].y)),
                       fmaxf(fabsf(v[c].z), fabsf(v[c].w))));
  }
#pragma unroll
  for (int off = 32; off; off >>= 1) m = fmaxf(m, __shfl_xor(m, off, 64));
  m = fmaxf(m, 1e-5f);
  const float r = 127.f / m;

#pragma unroll
  for (int c = 0; c < 16; ++c) {
    int q0 = (int)rintf(v[c].x * r);
    int q1 = (int)rintf(v[c].y * r);
    int q2 = (int)rintf(v[c].z * r);
    int q3 = (int)rintf(v[c].w * r);
    unsigned d = (q0 & 255) | ((q1 & 255) << 8) | ((q2 & 255) << 16) | ((q3 & 255) << 24);
    *(unsigned*)(XQ + (size_t)row * IN_F + c * 256 + lane * 4) = d;
  }
  if (lane == 0) XS[row] = m;
}

// ---------------- pass 1b: unpack ternary B once -> i8, chunk-major ----
// BQ layout: [c (k/16)][n][16 bytes]
__global__ __launch_bounds__(256)
void unpackB(const unsigned* __restrict__ PW, signed char* __restrict__ BQ) {
  const int g = blockIdx.x * 256 + threadIdx.x;   // 1M words
  const int c = g >> 12;                           // 0..255
  const int n = g & 4095;
  i32x4 u = unpack16(PW[(size_t)n * PACKED + c]);
  *(i32x4*)(BQ + ((size_t)c * OUT_F + n) * 16) = u;
}

// ---------------- pass 2 (fast): depth-2 pipelined i8 GEMM -------------
// Per wave per K-tile: 4 B reg loads + 4 global_load_lds = 8 vmem ops.
// Issue B(kt+1) then A(kt+2); vmcnt(12) keeps {A(kt+1), A(kt+2), B(kt+1)}
// in flight and drains exactly {A(kt), B(kt)}. One barrier per tile:
// it joins (a) everyone's kt data resident, (b) everyone done computing
// kt-1; stage(kt+2) overwrites the buffer of compute(kt-2), which is
// two barriers in the past -> WAR-safe with 4 buffers.

#define STAGE_A(BUF_, KT_)                                                      \
  {                                                                             \
    _Pragma("unroll")                                                           \
    for (int rb = 0; rb < 4; ++rb) {                                            \
      const signed char* src =                                                  \
          XQ + (size_t)(m0 + rb * 64 + lane) * IN_F + (KT_) * BK + w * 16;      \
      signed char* dst = lA + (BUF_) * 16384 + w * 4096 + rb * 1024;            \
      __builtin_amdgcn_global_load_lds(                                         \
          (const __attribute__((address_space(1))) void*)src,                   \
          (__attribute__((address_space(3))) void*)dst, 16, 0, 0);              \
    }                                                                           \
  }

#define LOAD_B(B_, KT_)                                                         \
  {                                                                             \
    _Pragma("unroll")                                                           \
    for (int nf = 0; nf < 2; ++nf) {                                            \
      _Pragma("unroll")                                                         \
      for (int ks = 0; ks < 2; ++ks)                                            \
        B_[nf][ks] = *(const i32x4*)(BQ +                                       \
            ((size_t)((KT_) * 4 + ks * 2 + h) * OUT_F + nrow[nf]) * 16);        \
      }                                                                         \
  }

#define COMPUTE(BUF_, B_)                                                       \
  {                                                                             \
    _Pragma("unroll")                                                           \
    for (int ks = 0; ks < 2; ++ks) {                                            \
      i32x4 afr[4];                                                             \
      _Pragma("unroll")                                                         \
      for (int mf = 0; mf < 4; ++mf)                                            \
        afr[mf] = *(const i32x4*)(lA + (BUF_) * 16384 + (ks * 2 + h) * 4096 +   \
                                  (wm * 128 + mf * 32 + l31) * 16);             \
      __builtin_amdgcn_s_setprio(1);                                            \
      _Pragma("unroll")                                                         \
      for (int mf = 0; mf < 4; ++mf) {                                          \
        acc[mf][0] = __builtin_amdgcn_mfma_i32_32x32x32_i8(afr[mf], B_[0][ks],  \
                                                           acc[mf][0], 0, 0, 0);\
        acc[mf][1] = __builtin_amdgcn_mfma_i32_32x32x32_i8(afr[mf], B_[1][ks],  \
                                                           acc[mf][1], 0, 0, 0);\
      }                                                                         \
      __builtin_amdgcn_s_setprio(0);                                            \
    }                                                                           \
  }

#define BODY(KT_, BUFC_, BUFS_, BC_, BL_, DOB_, DOA_, VM_)                      \
  {                                                                             \
    if (DOB_) LOAD_B(BL_, (KT_) + 1);                                           \
    if (DOA_) STAGE_A(BUFS_, (KT_) + 2);                                        \
    asm volatile("s_waitcnt vmcnt(" #VM_ ")" ::: "memory");                     \
    __builtin_amdgcn_s_barrier();                                               \
    asm volatile("" ::: "memory");                                              \
    COMPUTE(BUFC_, BC_);                                                        \
  }

__global__ __launch_bounds__(NTHR, 2)
void gemm_i8(const signed char* __restrict__ XQ, const signed char* __restrict__ BQ,
             const float* __restrict__ XS, const float* __restrict__ SC,
             float* __restrict__ OUT) {
  __shared__ signed char lA[4 * 16384];   // 64 KB quad-buffer

  const int tid  = threadIdx.x;
  const int lane = tid & 63;
  const int w    = tid >> 6;     // 0..3
  const int wm   = w >> 1;       // 0..1 (M half)
  const int wn   = w & 1;        // 0..1 (N half)
  const int l31  = lane & 31;
  const int h    = lane >> 5;    // half-wave -> k-chunk parity

  // bijective XCD swizzle: 1024 blocks = 8 XCD x 128; each XCD owns 4
  // n-tiles (BQ stripe 512 cols x 4 KB = 2 MB < 4 MB L2)
  const int orig = blockIdx.y * gridDim.x + blockIdx.x;
  const int xcd  = orig & 7;
  const int idx  = orig >> 3;                  // 0..127
  const int m0   = (idx >> 2) * BM;            // 32 m-tiles
  const int n0   = (xcd * 4 + (idx & 3)) * BN; // 32 n-tiles

  const int nrow[2] = { n0 + wn * 64 + 0 * 32 + l31,
                        n0 + wn * 64 + 1 * 32 + l31 };

  i32x16 acc[4][2];
#pragma unroll
  for (int mf = 0; mf < 4; ++mf)
#pragma unroll
    for (int nf = 0; nf < 2; ++nf)
      acc[mf][nf] = (i32x16)(0);

  i32x4 Ba[2][2], Bb[2][2];

  // prologue: B(0), A(0)->buf0, A(1)->buf1 in flight
  LOAD_B(Ba, 0);
  STAGE_A(0, 0);
  STAGE_A(1, 1);

  // main: kt = 0..59 in unrolled groups of 4 (static buffer indices)
  for (int kt0 = 0; kt0 < NT - 4; kt0 += 4) {
    BODY(kt0 + 0, 0, 2, Ba, Bb, true, true, 12);
    BODY(kt0 + 1, 1, 3, Bb, Ba, true, true, 12);
    BODY(kt0 + 2, 2, 0, Ba, Bb, true, true, 12);
    BODY(kt0 + 3, 3, 1, Bb, Ba, true, true, 12);
  }
  // tail: kt = 60..63
  BODY(NT - 4, 0, 2, Ba, Bb, true,  true,  12);
  BODY(NT - 3, 1, 3, Bb, Ba, true,  true,  12);
  BODY(NT - 2, 2, 0, Ba, Bb, true,  false, 8);
  BODY(NT - 1, 3, 0, Bb, Ba, false, false, 0);

  // ---- epilogue: C/D (32x32): col=lane&31, row=(reg&3)+8*(reg>>2)+4*h ----
  const float sc = SC[0] / 127.f;
#pragma unroll
  for (int mf = 0; mf < 4; ++mf) {
    float fs[16];
#pragma unroll
    for (int r = 0; r < 16; ++r) {
      const int mm = m0 + wm * 128 + mf * 32 + 4 * h + (r & 3) + 8 * (r >> 2);
      fs[r] = sc * XS[mm];
    }
#pragma unroll
    for (int nf = 0; nf < 2; ++nf) {
      const int ncol = n0 + wn * 64 + nf * 32 + l31;
#pragma unroll
      for (int r = 0; r < 16; ++r) {
        const int mm = m0 + wm * 128 + mf * 32 + 4 * h + (r & 3) + 8 * (r >> 2);
        OUT[(size_t)mm * OUT_F + ncol] = (float)acc[mf][nf][r] * fs[r];
      }
    }
  }
}

// ------- pass 2 (fallback, ws-small): verified baseline gemm, inline B -------
__global__ __launch_bounds__(256, 2)
void gemm_i8_pw(const signed char* __restrict__ XQ, const unsigned* __restrict__ PW,
                const float* __restrict__ XS, const float* __restrict__ SC,
                float* __restrict__ OUT) {
  __shared__ signed char lA[256 * 128];

  const int tid  = threadIdx.x;
  const int lane = tid & 63;
  const int w    = tid >> 6;
  const int wm   = w >> 1;
  const int wn   = w & 1;
  const int l31  = lane & 31;
  const int h    = lane >> 5;

  const int m0 = blockIdx.y * 256;
  const int n0 = blockIdx.x * 128;

  i32x16 acc[4][2];
#pragma unroll
  for (int mf = 0; mf < 4; ++mf)
#pragma unroll
    for (int nf = 0; nf < 2; ++nf)
      acc[mf][nf] = (i32x16)(0);

  const unsigned* pb0 = PW + (size_t)(n0 + wn * 64 + 0 * 32 + l31) * PACKED;
  const unsigned* pb1 = PW + (size_t)(n0 + wn * 64 + 1 * 32 + l31) * PACKED;

  for (int kt = 0; kt < IN_F / 128; ++kt) {
#pragma unroll
    for (int cc = 0; cc < 2; ++cc) {
      const int c = w * 2 + cc;
#pragma unroll
      for (int rb = 0; rb < 4; ++rb) {
        const signed char* src =
            XQ + (size_t)(m0 + rb * 64 + lane) * IN_F + kt * 128 + c * 16;
        signed char* dst = lA + c * 4096 + rb * 1024;
        __builtin_amdgcn_global_load_lds(
            (const __attribute__((address_space(1))) void*)src,
            (__attribute__((address_space(3))) void*)dst, 16, 0, 0);
      }
    }

    unsigned bw0[4], bw1[4];
#pragma unroll
    for (int ks = 0; ks < 4; ++ks) {
      bw0[ks] = pb0[kt * 8 + ks * 2 + h];
      bw1[ks] = pb1[kt * 8 + ks * 2 + h];
    }

    __syncthreads();

#pragma unroll
    for (int ks = 0; ks < 4; ++ks) {
      i32x4 bfr0 = unpack16(bw0[ks]);
      i32x4 bfr1 = unpack16(bw1[ks]);
      i32x4 afr[4];
#pragma unroll
      for (int mf = 0; mf < 4; ++mf)
        afr[mf] = *(const i32x4*)(lA + (ks * 2 + h) * 4096 +
                                  (wm * 128 + mf * 32 + l31) * 16);
#pragma unroll
      for (int mf = 0; mf < 4; ++mf) {
        acc[mf][0] = __builtin_amdgcn_mfma_i32_32x32x32_i8(afr[mf], bfr0, acc[mf][0], 0, 0, 0);
        acc[mf][1] = __builtin_amdgcn_mfma_i32_32x32x32_i8(afr[mf], bfr1, acc[mf][1], 0, 0, 0);
      }
    }
    __syncthreads();
  }

  const float sc = SC[0] / 127.f;
#pragma unroll
  for (int mf = 0; mf < 4; ++mf) {
    float fs[16];
#pragma unroll
    for (int r = 0; r < 16; ++r) {
      const int mm = m0 + wm * 128 + mf * 32 + 4 * h + (r & 3) + 8 * (r >> 2);
      fs[r] = sc * XS[mm];
    }
#pragma unroll
    for (int nf = 0; nf < 2; ++nf) {
      const int ncol = n0 + wn * 64 + nf * 32 + l31;
#pragma unroll
      for (int r = 0; r < 16; ++r) {
        const int mm = m0 + wm * 128 + mf * 32 + 4 * h + (r & 3) + 8 * (r >> 2);
        OUT[(size_t)mm * OUT_F + ncol] = (float)acc[mf][nf][r] * fs[r];
      }
    }
  }
}

extern "C" void kernel_launch(void* const* d_in, const int* in_sizes, int n_in,
                              void* d_out, int out_size, void* d_ws, size_t ws_size,
                              hipStream_t stream) {
  const float*    x  = (const float*)d_in[0];
  const unsigned* pw = (const unsigned*)d_in[1];
  const float*    sc = (const float*)d_in[2];
  float*          out = (float*)d_out;

  signed char* xq = (signed char*)d_ws;
  float*       xs = (float*)((char*)d_ws + XQ_BYTES);

  rowquant<<<dim3(TOKENS / 4), dim3(256), 0, stream>>>(x, xq, xs);

  if (ws_size >= WS_NEED) {
    // fast path: pre-unpacked B + depth-2 pipelined gemm
    signed char* bq = (signed char*)d_ws + BQ_OFF;
    unpackB<<<dim3(OUT_F * PACKED / 256), dim3(256), 0, stream>>>(pw, bq);
    dim3 grid(OUT_F / BN, TOKENS / BM);  // (32, 32)
    gemm_i8<<<grid, dim3(NTHR), 0, stream>>>(xq, bq, xs, sc, out);
  } else {
    // fallback: verified baseline gemm, inline ternary unpack (fits 33.6 MB ws)
    dim3 grid(OUT_F / 128, TOKENS / 256);  // (32, 32)
    gemm_i8_pw<<<grid, dim3(256), 0, stream>>>(xq, pw, xs, sc, out);
  }
}

// Round 9
// 397.019 us; speedup vs baseline: 1.3561x; 1.0750x over previous
//
#include <hip/hip_runtime.h>
#include <math.h>

typedef __attribute__((ext_vector_type(4)))  int   i32x4;
typedef __attribute__((ext_vector_type(16))) int   i32x16;
typedef __attribute__((ext_vector_type(4)))  float f32x4;

namespace {
constexpr int IN_F   = 4096;
constexpr int OUT_F  = 4096;
constexpr int TOKENS = 8192;
constexpr int PACKED = IN_F / 16;      // 256 words per weight row

// fast-path gemm: 256x256 block, 8 waves (2M x 4N), wave tile 128x64,
// BK=128, A+B both LDS-staged (128 KB double buffer), 4-phase interleave.
constexpr int BM   = 256;
constexpr int BN   = 256;
constexpr int BK   = 128;              // 8 chunks of 16 k
constexpr int NTHR = 512;
constexpr int NT   = IN_F / BK;        // 32 K-tiles

constexpr size_t XQ_BYTES = (size_t)TOKENS * IN_F;        // 33.55 MB
constexpr size_t XS_BYTES = (size_t)TOKENS * 4;           // 32 KB
constexpr size_t BQ_OFF   = XQ_BYTES + XS_BYTES;
constexpr size_t BQ_BYTES = (size_t)PACKED * OUT_F * 16;  // 16.78 MB
constexpr size_t WS_NEED  = BQ_OFF + BQ_BYTES;            // ~50.4 MB
}

// 16x 2-bit {0,1,2}  ->  16x i8 {-1,0,1}  (4 dwords)
__device__ __forceinline__ i32x4 unpack16(unsigned w) {
  i32x4 r;
#pragma unroll
  for (int g = 0; g < 4; ++g) {
    unsigned t = (w >> (8 * g)) & 0xFFu;
    unsigned s = (t | (t << 6) | (t << 12) | (t << 18)) & 0x03030303u;
    r[g] = (int)((((s | 0x80808080u) - 0x01010101u) ^ 0x80808080u));
  }
  return r;
}

// ------- pass 1 (fused): rowquant (blocks 0..2047) + unpackB (rest) -------
__global__ __launch_bounds__(256)
void prep(const float* __restrict__ X, signed char* __restrict__ XQ,
          float* __restrict__ XS, const unsigned* __restrict__ PW,
          signed char* __restrict__ BQ) {
  if (blockIdx.x < TOKENS / 4) {
    const int row  = blockIdx.x * 4 + (threadIdx.x >> 6);
    const int lane = threadIdx.x & 63;
    const float* xr = X + (size_t)row * IN_F;

    f32x4 v[16];
    float m = 0.f;
#pragma unroll
    for (int c = 0; c < 16; ++c) {
      v[c] = *(const f32x4*)(xr + c * 256 + lane * 4);
      m = fmaxf(m, fmaxf(fmaxf(fabsf(v[c].x), fabsf(v[c].y)),
                         fmaxf(fabsf(v[c].z), fabsf(v[c].w))));
    }
#pragma unroll
    for (int off = 32; off; off >>= 1) m = fmaxf(m, __shfl_xor(m, off, 64));
    m = fmaxf(m, 1e-5f);
    const float r = 127.f / m;

#pragma unroll
    for (int c = 0; c < 16; ++c) {
      int q0 = (int)rintf(v[c].x * r);
      int q1 = (int)rintf(v[c].y * r);
      int q2 = (int)rintf(v[c].z * r);
      int q3 = (int)rintf(v[c].w * r);
      unsigned d = (q0 & 255) | ((q1 & 255) << 8) | ((q2 & 255) << 16) | ((q3 & 255) << 24);
      *(unsigned*)(XQ + (size_t)row * IN_F + c * 256 + lane * 4) = d;
    }
    if (lane == 0) XS[row] = m;
  } else {
    // BQ layout: [c (k/16)][n][16 bytes]
    const int g = (blockIdx.x - TOKENS / 4) * 256 + threadIdx.x;  // 1M words
    const int c = g >> 12;                                         // 0..255
    const int n = g & 4095;
    i32x4 u = unpack16(PW[(size_t)n * PACKED + c]);
    *(i32x4*)(BQ + ((size_t)c * OUT_F + n) * 16) = u;
  }
}

// ---------------- pass 2 (fast): 4-phase interleaved i8 GEMM ------------
// Per wave per tile: 4 A-stage + 4 B-stage global_load_lds (issued in P0/P1,
// one full tile before use) + per phase {4+2 ds_read_b128, 8 MFMA w/ setprio}.
// vmcnt(0)+barrier once per tile: drains only tile-old loads (free), swaps.

#define STAGE_A(BUF_, KT_)                                                      \
  {                                                                             \
    _Pragma("unroll")                                                           \
    for (int rb = 0; rb < 4; ++rb) {                                            \
      const signed char* src =                                                  \
          XQ + (size_t)(m0 + rb * 64 + lane) * IN_F + (KT_) * BK + w * 16;      \
      signed char* dst = lA + (BUF_) * 32768 + w * 4096 + rb * 1024;            \
      __builtin_amdgcn_global_load_lds(                                         \
          (const __attribute__((address_space(1))) void*)src,                   \
          (__attribute__((address_space(3))) void*)dst, 16, 0, 0);              \
    }                                                                           \
  }

#define STAGE_B(BUF_, KT_)                                                      \
  {                                                                             \
    _Pragma("unroll")                                                           \
    for (int j = 0; j < 4; ++j) {                                               \
      const signed char* src =                                                  \
          BQ + ((size_t)((KT_) * 8 + w) * OUT_F + n0 + j * 64 + lane) * 16;     \
      signed char* dst = lB + (BUF_) * 32768 + w * 4096 + j * 1024;             \
      __builtin_amdgcn_global_load_lds(                                         \
          (const __attribute__((address_space(1))) void*)src,                   \
          (__attribute__((address_space(3))) void*)dst, 16, 0, 0);              \
    }                                                                           \
  }

#define PHASE(KS_, BUF_)                                                        \
  {                                                                             \
    i32x4 afr[4], bfr[2];                                                       \
    _Pragma("unroll")                                                           \
    for (int mf = 0; mf < 4; ++mf)                                              \
      afr[mf] = *(const i32x4*)(lA + (BUF_) * 32768 + ((KS_) * 2 + h) * 4096 +  \
                                (wm * 128 + mf * 32 + l31) * 16);               \
    _Pragma("unroll")                                                           \
    for (int nf = 0; nf < 2; ++nf)                                              \
      bfr[nf] = *(const i32x4*)(lB + (BUF_) * 32768 + ((KS_) * 2 + h) * 4096 +  \
                                (wn * 64 + nf * 32 + l31) * 16);                \
    __builtin_amdgcn_s_setprio(1);                                              \
    _Pragma("unroll")                                                           \
    for (int mf = 0; mf < 4; ++mf) {                                            \
      acc[mf][0] = __builtin_amdgcn_mfma_i32_32x32x32_i8(afr[mf], bfr[0],       \
                                                         acc[mf][0], 0, 0, 0);  \
      acc[mf][1] = __builtin_amdgcn_mfma_i32_32x32x32_i8(afr[mf], bfr[1],       \
                                                         acc[mf][1], 0, 0, 0);  \
    }                                                                           \
    __builtin_amdgcn_s_setprio(0);                                              \
  }

#define TILE(KT_, CUR_, NXT_, PF_)                                              \
  {                                                                             \
    if (PF_) STAGE_A(NXT_, (KT_) + 1);                                          \
    PHASE(0, CUR_)                                                              \
    if (PF_) STAGE_B(NXT_, (KT_) + 1);                                          \
    PHASE(1, CUR_)                                                              \
    PHASE(2, CUR_)                                                              \
    PHASE(3, CUR_)                                                              \
    asm volatile("s_waitcnt vmcnt(0)" ::: "memory");                            \
    __builtin_amdgcn_s_barrier();                                               \
  }

__global__ __launch_bounds__(NTHR, 2)
void gemm_i8(const signed char* __restrict__ XQ, const signed char* __restrict__ BQ,
             const float* __restrict__ XS, const float* __restrict__ SC,
             float* __restrict__ OUT) {
  __shared__ signed char lA[2 * 32768];   // A: [buf][chunk c][row m][16]
  __shared__ signed char lB[2 * 32768];   // B: [buf][chunk c][col n][16]

  const int tid  = threadIdx.x;
  const int lane = tid & 63;
  const int w    = tid >> 6;     // 0..7
  const int wm   = w >> 2;       // 0..1 (M half)
  const int wn   = w & 3;        // 0..3 (N quarter)
  const int l31  = lane & 31;
  const int h    = lane >> 5;    // half-wave -> k-chunk parity

  // bijective XCD swizzle: 512 blocks = 8 XCD x 64; each XCD owns 2 n-tiles
  // (BQ stripe 512 cols x 256 chunks x 16B = 2 MB < 4 MB L2)
  const int orig = blockIdx.y * gridDim.x + blockIdx.x;
  const int xcd  = orig & 7;
  const int idx  = orig >> 3;                  // 0..63
  const int m0   = (idx >> 1) * BM;            // 32 m-tiles
  const int n0   = (xcd * 2 + (idx & 1)) * BN; // 16 n-tiles

  i32x16 acc[4][2];
#pragma unroll
  for (int mf = 0; mf < 4; ++mf)
#pragma unroll
    for (int nf = 0; nf < 2; ++nf)
      acc[mf][nf] = (i32x16)(0);

  // prologue: tile 0 into buf0
  STAGE_A(0, 0);
  STAGE_B(0, 0);
  asm volatile("s_waitcnt vmcnt(0)" ::: "memory");
  __builtin_amdgcn_s_barrier();

  for (int kt = 0; kt < NT - 2; kt += 2) {
    TILE(kt,     0, 1, true);
    TILE(kt + 1, 1, 0, true);
  }
  TILE(NT - 2, 0, 1, true);
  TILE(NT - 1, 1, 0, false);

  // ---- epilogue: C/D (32x32): col=lane&31, row=(reg&3)+8*(reg>>2)+4*h ----
  const float sc = SC[0] / 127.f;
#pragma unroll
  for (int mf = 0; mf < 4; ++mf) {
    float fs[16];
#pragma unroll
    for (int r = 0; r < 16; ++r) {
      const int mm = m0 + wm * 128 + mf * 32 + 4 * h + (r & 3) + 8 * (r >> 2);
      fs[r] = sc * XS[mm];
    }
#pragma unroll
    for (int nf = 0; nf < 2; ++nf) {
      const int ncol = n0 + wn * 64 + nf * 32 + l31;
#pragma unroll
      for (int r = 0; r < 16; ++r) {
        const int mm = m0 + wm * 128 + mf * 32 + 4 * h + (r & 3) + 8 * (r >> 2);
        OUT[(size_t)mm * OUT_F + ncol] = (float)acc[mf][nf][r] * fs[r];
      }
    }
  }
}

// ------- pass 2 (fallback, ws-small): verified baseline gemm, inline B -------
__global__ __launch_bounds__(256, 2)
void gemm_i8_pw(const signed char* __restrict__ XQ, const unsigned* __restrict__ PW,
                const float* __restrict__ XS, const float* __restrict__ SC,
                float* __restrict__ OUT) {
  __shared__ signed char lA[256 * 128];

  const int tid  = threadIdx.x;
  const int lane = tid & 63;
  const int w    = tid >> 6;
  const int wm   = w >> 1;
  const int wn   = w & 1;
  const int l31  = lane & 31;
  const int h    = lane >> 5;

  const int m0 = blockIdx.y * 256;
  const int n0 = blockIdx.x * 128;

  i32x16 acc[4][2];
#pragma unroll
  for (int mf = 0; mf < 4; ++mf)
#pragma unroll
    for (int nf = 0; nf < 2; ++nf)
      acc[mf][nf] = (i32x16)(0);

  const unsigned* pb0 = PW + (size_t)(n0 + wn * 64 + 0 * 32 + l31) * PACKED;
  const unsigned* pb1 = PW + (size_t)(n0 + wn * 64 + 1 * 32 + l31) * PACKED;

  for (int kt = 0; kt < IN_F / 128; ++kt) {
#pragma unroll
    for (int cc = 0; cc < 2; ++cc) {
      const int c = w * 2 + cc;
#pragma unroll
      for (int rb = 0; rb < 4; ++rb) {
        const signed char* src =
            XQ + (size_t)(m0 + rb * 64 + lane) * IN_F + kt * 128 + c * 16;
        signed char* dst = lA + c * 4096 + rb * 1024;
        __builtin_amdgcn_global_load_lds(
            (const __attribute__((address_space(1))) void*)src,
            (__attribute__((address_space(3))) void*)dst, 16, 0, 0);
      }
    }

    unsigned bw0[4], bw1[4];
#pragma unroll
    for (int ks = 0; ks < 4; ++ks) {
      bw0[ks] = pb0[kt * 8 + ks * 2 + h];
      bw1[ks] = pb1[kt * 8 + ks * 2 + h];
    }

    __syncthreads();

#pragma unroll
    for (int ks = 0; ks < 4; ++ks) {
      i32x4 bfr0 = unpack16(bw0[ks]);
      i32x4 bfr1 = unpack16(bw1[ks]);
      i32x4 afr[4];
#pragma unroll
      for (int mf = 0; mf < 4; ++mf)
        afr[mf] = *(const i32x4*)(lA + (ks * 2 + h) * 4096 +
                                  (wm * 128 + mf * 32 + l31) * 16);
#pragma unroll
      for (int mf = 0; mf < 4; ++mf) {
        acc[mf][0] = __builtin_amdgcn_mfma_i32_32x32x32_i8(afr[mf], bfr0, acc[mf][0], 0, 0, 0);
        acc[mf][1] = __builtin_amdgcn_mfma_i32_32x32x32_i8(afr[mf], bfr1, acc[mf][1], 0, 0, 0);
      }
    }
    __syncthreads();
  }

  const float sc = SC[0] / 127.f;
#pragma unroll
  for (int mf = 0; mf < 4; ++mf) {
    float fs[16];
#pragma unroll
    for (int r = 0; r < 16; ++r) {
      const int mm = m0 + wm * 128 + mf * 32 + 4 * h + (r & 3) + 8 * (r >> 2);
      fs[r] = sc * XS[mm];
    }
#pragma unroll
    for (int nf = 0; nf < 2; ++nf) {
      const int ncol = n0 + wn * 64 + nf * 32 + l31;
#pragma unroll
      for (int r = 0; r < 16; ++r) {
        const int mm = m0 + wm * 128 + mf * 32 + 4 * h + (r & 3) + 8 * (r >> 2);
        OUT[(size_t)mm * OUT_F + ncol] = (float)acc[mf][nf][r] * fs[r];
      }
    }
  }
}

extern "C" void kernel_launch(void* const* d_in, const int* in_sizes, int n_in,
                              void* d_out, int out_size, void* d_ws, size_t ws_size,
                              hipStream_t stream) {
  const float*    x  = (const float*)d_in[0];
  const unsigned* pw = (const unsigned*)d_in[1];
  const float*    sc = (const float*)d_in[2];
  float*          out = (float*)d_out;

  signed char* xq = (signed char*)d_ws;
  float*       xs = (float*)((char*)d_ws + XQ_BYTES);

  if (ws_size >= WS_NEED) {
    // fast path: fused prep + 4-phase interleaved gemm
    signed char* bq = (signed char*)d_ws + BQ_OFF;
    prep<<<dim3(TOKENS / 4 + OUT_F * PACKED / 256), dim3(256), 0, stream>>>(
        x, xq, xs, pw, bq);
    dim3 grid(OUT_F / BN, TOKENS / BM);  // (16, 32)
    gemm_i8<<<grid, dim3(NTHR), 0, stream>>>(xq, bq, xs, sc, out);
  } else {
    // fallback: verified baseline gemm, inline ternary unpack (fits 33.6 MB ws)
    prep<<<dim3(TOKENS / 4), dim3(256), 0, stream>>>(x, xq, xs, pw, nullptr);
    dim3 grid(OUT_F / 128, TOKENS / 256);  // (32, 32)
    gemm_i8_pw<<<grid, dim3(256), 0, stream>>>(xq, pw, xs, sc, out);
  }
}